// Round 11
// baseline (248.119 us; speedup 1.0000x reference)
//
#include <hip/hip_runtime.h>
#include <hip/hip_bf16.h>

typedef __hip_bfloat16 bf16;
typedef __attribute__((ext_vector_type(8))) short short8;
typedef __attribute__((ext_vector_type(4))) float f32x4;
typedef __attribute__((ext_vector_type(2))) float f32x2;

#define HID 64
#define CAP 4096            // slots per 128-node bucket (mean fill ~2048; P(>4096)~0)
#define BSH 7               // bucket = node >> 7
#define EPB 2048            // edges per bin block (782 blocks; 2 blocks/CU resident)

__device__ __forceinline__ unsigned short f2bfbits(float x){
    union { float f; unsigned u; } c; c.f = x;
    unsigned r = c.u + 0x7fffu + ((c.u >> 16) & 1u);
    return (unsigned short)(r >> 16);
}
__device__ __forceinline__ unsigned char f2fp8(float x){
    unsigned v = __builtin_amdgcn_cvt_pk_fp8_f32(x, x, 0u, false);
    return (unsigned char)(v & 0xffu);
}
template<bool HI>
__device__ __forceinline__ f32x2 cvtpk(unsigned u){
    return __builtin_amdgcn_cvt_pk_f32_fp8(u, HI);
}

// ---------------- pass 1: bin edges by destination bucket (R10-proven) ----------------

__global__ __launch_bounds__(1024) void bin_kernel(const int* __restrict__ row,
                                                   const int* __restrict__ col,
                                                   int E, int NB,
                                                   int* __restrict__ gCur,
                                                   int* __restrict__ binned,
                                                   unsigned char* __restrict__ H8a,
                                                   unsigned char* __restrict__ H8b,
                                                   int N){
    __shared__ int lCnt[1024];
    __shared__ int lOff[1024];
    __shared__ int lGB[1024];
    __shared__ int sPay[EPB];
    __shared__ unsigned short sB[EPB];
    __shared__ int wSum[16];
    int tid = threadIdx.x;
    int lane = tid & 63, wv = tid >> 6;
    if (blockIdx.x == 0 && tid < 32){
        unsigned* za = (unsigned*)(H8a + ((size_t)N << 6));
        unsigned* zb = (unsigned*)(H8b + ((size_t)N << 6));
        if (tid < 16) za[tid] = 0u; else zb[tid - 16] = 0u;
    }
    int e0 = blockIdx.x * EPB;
    int eN = E - e0; if (eN > EPB) eN = EPB;

    lCnt[tid] = 0;
    int cols[2], rows[2];
    #pragma unroll
    for (int k = 0; k < 2; ++k){
        int i = tid + k * 1024;
        bool ok = (i < eN);
        cols[k] = ok ? col[e0 + i] : -1;
        rows[k] = ok ? row[e0 + i] : 0;
    }
    __syncthreads();
    #pragma unroll
    for (int k = 0; k < 2; ++k)
        if (cols[k] >= 0) atomicAdd(&lCnt[cols[k] >> BSH], 1);
    __syncthreads();

    int c = lCnt[tid];
    int inc = c;
    #pragma unroll
    for (int m = 1; m < 64; m <<= 1){
        int t = __shfl_up(inc, m);
        if (lane >= m) inc += t;
    }
    if (lane == 63) wSum[wv] = inc;
    __syncthreads();
    if (wv == 0 && lane < 16){
        int orig = wSum[lane];
        int ws = orig;
        #pragma unroll
        for (int m = 1; m < 16; m <<= 1){
            int t = __shfl_up(ws, m);
            if (lane >= m) ws += t;
        }
        wSum[lane] = ws - orig;
    }
    __syncthreads();
    int excl = inc - c + wSum[wv];
    lOff[tid] = excl;
    if (c){
        int gb = atomicAdd(&gCur[tid], c);
        lGB[tid] = tid * CAP + gb - excl;
    }
    lCnt[tid] = 0;
    __syncthreads();

    #pragma unroll
    for (int k = 0; k < 2; ++k){
        if (cols[k] >= 0){
            int bk = cols[k] >> BSH;
            int rk = atomicAdd(&lCnt[bk], 1);
            int pos = lOff[bk] + rk;
            sPay[pos] = ((cols[k] & 127) << 17) | rows[k];
            sB[pos] = (unsigned short)bk;
        }
    }
    __syncthreads();

    #pragma unroll
    for (int k = 0; k < 2; ++k){
        int i = tid + k * 1024;
        if (i < eN){
            int bk = sB[i];
            int tgt = lGB[bk] + i;
            if (tgt - (bk << 12) < CAP)
                binned[tgt] = sPay[i];
        }
    }
}

// ---------------- pass 2: degrees + col_ptr + degree-sorted perm ----------------
// One block per bucket. NEW: per-64-node window, emit a degree-sorted permutation
// (64-lane shfl rank sort) so agg waves get similar-degree nodes -> wave-max degree
// loop trips drop ~30% (Poisson(16): E[max of 16] ~ 27 vs sorted-chunk ~19 avg).

__global__ __launch_bounds__(256) void degree_kernel(const int* __restrict__ gCur,
                                                     const int* __restrict__ binned,
                                                     int* __restrict__ col_ptr,
                                                     int* __restrict__ cnt,
                                                     int* __restrict__ perm, int N){
    __shared__ int fineCnt[128];
    __shared__ int scW[2];
    int b = blockIdx.x, tid = threadIdx.x;
    int j0 = b * CAP;
    int c = gCur[b];
    if (c > CAP) c = CAP;
    if (tid < 128) fineCnt[tid] = 0;
    __syncthreads();
    for (int i = tid; i < c; i += 256)
        atomicAdd(&fineCnt[binned[j0 + i] >> 17], 1);
    __syncthreads();
    int cf = 0, inc = 0;
    if (tid < 128){
        cf = fineCnt[tid];
        inc = cf;
        #pragma unroll
        for (int m = 1; m < 64; m <<= 1){
            int t = __shfl_up(inc, m);
            if ((tid & 63) >= m) inc += t;
        }
        if ((tid & 63) == 63) scW[tid >> 6] = inc;
    }
    __syncthreads();
    if (tid < 128){
        int lane = tid & 63, w = tid >> 6;
        int off = (tid >= 64) ? scW[0] : 0;
        int node = (b << BSH) + tid;
        bool v = (node < N);
        if (v){
            col_ptr[node] = j0 + off + inc - cf;
            cnt[node] = cf;
        }
        // degree-sorted rank within this 64-node window (invalid nodes sort last)
        int key = v ? cf : 0x7fffffff;
        int rank = 0;
        for (int j = 0; j < 64; ++j){
            int kj = __shfl(key, j);
            rank += (kj < key) || (kj == key && j < lane);
        }
        perm[(b << BSH) + (w << 6) + rank] = v ? node : N;
    }
}

// ---------------- MFMA matmul (layer 1): H[N,64](fp8) = rsqrt(cnt+1)*(x[N,128]@W1) ----------------

template<int K, typename T>
__global__ __launch_bounds__(256) void matmul_kernel(const T* __restrict__ act,
                                                     const float* __restrict__ W,
                                                     const int* __restrict__ cnt,
                                                     unsigned char* __restrict__ H8, int N){
    constexpr int KS = K / 32;
    constexpr int RB = 2 * K;
    __shared__ __align__(16) short As[128 * K];
    __shared__ __align__(16) short Wt[64 * K];

    int tid = threadIdx.x;
    int nodeBase = blockIdx.x * 128;

    for (int i = tid; i < K * 64; i += 256){
        int k = i >> 6, c = i & 63;
        unsigned short b = f2bfbits(W[i]);
        int byte = c * RB + ((2 * k) ^ ((c & 7) << 4));
        *(short*)((char*)Wt + byte) = (short)b;
    }
    constexpr int OPR = K / 8;
    for (int i = tid; i < 128 * OPR; i += 256){
        int node = i / OPR, oct = i % OPR;
        int n = nodeBase + node;
        short8 v = (short8)0;
        if (n < N){
            if constexpr (sizeof(T) == 4){
                const float4* xp = (const float4*)&act[(size_t)n * K + oct * 8];
                float4 a = xp[0], b = xp[1];
                v[0] = (short)f2bfbits(a.x); v[1] = (short)f2bfbits(a.y);
                v[2] = (short)f2bfbits(a.z); v[3] = (short)f2bfbits(a.w);
                v[4] = (short)f2bfbits(b.x); v[5] = (short)f2bfbits(b.y);
                v[6] = (short)f2bfbits(b.z); v[7] = (short)f2bfbits(b.w);
            } else {
                v = *(const short8*)&act[(size_t)n * K + oct * 8];
            }
        }
        int byte = node * RB + ((oct * 16) ^ ((node & 7) << 4));
        *(short8*)((char*)As + byte) = v;
    }
    __syncthreads();

    int wv = tid >> 6, l = tid & 63;
    int lr = l & 15, lg = l >> 4;

    short8 bfr[KS][4];
    #pragma unroll
    for (int ks = 0; ks < KS; ++ks)
        #pragma unroll
        for (int t = 0; t < 4; ++t){
            int c = t * 16 + lr;
            int byte = c * RB + ((ks * 64 + lg * 16) ^ ((c & 7) << 4));
            bfr[ks][t] = *(const short8*)((const char*)Wt + byte);
        }

    #pragma unroll
    for (int nt = 0; nt < 2; ++nt){
        int nb = wv * 32 + nt * 16;
        int node = nb + lr;
        short8 af[KS];
        #pragma unroll
        for (int ks = 0; ks < KS; ++ks){
            int byte = node * RB + ((ks * 64 + lg * 16) ^ ((node & 7) << 4));
            af[ks] = *(const short8*)((const char*)As + byte);
        }
        f32x4 acc[4] = {(f32x4)0.f, (f32x4)0.f, (f32x4)0.f, (f32x4)0.f};
        #pragma unroll
        for (int ks = 0; ks < KS; ++ks)
            #pragma unroll
            for (int t = 0; t < 4; ++t)
                acc[t] = __builtin_amdgcn_mfma_f32_16x16x32_bf16(af[ks], bfr[ks][t], acc[t], 0, 0, 0);
        #pragma unroll
        for (int r = 0; r < 4; ++r){
            int n = nodeBase + nb + lg * 4 + r;
            if (n < N){
                float dv = rsqrtf((float)cnt[n] + 1.0f);
                #pragma unroll
                for (int t = 0; t < 4; ++t)
                    H8[((size_t)(unsigned)n << 6) + t * 16 + lr] = f2fp8(acc[t][r] * dv);
            }
        }
    }
}

// ---------------- layer-1 fused: rank-scatter + agg (perm'd) + LN + matmul(W2) ----------------

__global__ __launch_bounds__(512) void agg_sort_kernel(const unsigned char* __restrict__ H8in,
                                                       const int* __restrict__ cnt,
                                                       const int* __restrict__ gCur,
                                                       const int* __restrict__ binned,
                                                       const int* __restrict__ col_ptr,
                                                       const int* __restrict__ perm,
                                                       int* __restrict__ csr_row,
                                                       const float* __restrict__ bias,
                                                       const float* __restrict__ lnw,
                                                       const float* __restrict__ lnb,
                                                       const float* __restrict__ Wn,
                                                       unsigned char* __restrict__ H8out,
                                                       int N){
    __shared__ int sCsr[CAP];
    __shared__ __align__(16) short ybuf[8192];
    __shared__ __align__(16) short Wt[4096];
    __shared__ int fineCur[128];
    __shared__ float sdv[128];
    __shared__ int sperm[128];
    int b = blockIdx.x, tid = threadIdx.x;
    int wid = tid >> 6, l = tid & 63;
    int g = l >> 2, s = l & 3;
    int nodeBase = b << BSH;

    int j0g = b * CAP;
    int cntB = gCur[b];
    if (cntB > CAP) cntB = CAP;

    for (int i = tid; i < 4096; i += 512){
        int k = i >> 6, c = i & 63;
        unsigned short bb = f2bfbits(Wn[i]);
        int byte = c * 128 + ((2 * k) ^ ((c & 7) << 4));
        *(short*)((char*)Wt + byte) = (short)bb;
    }
    if (tid < 128){
        int node = nodeBase + tid;
        fineCur[tid] = (node < N) ? (col_ptr[node] - j0g) : 0;
    }
    __syncthreads();

    for (int i = tid; i < cntB; i += 512){
        int w = binned[j0g + i];
        int pos = atomicAdd(&fineCur[w >> 17], 1);
        sCsr[pos] = w & 0x1FFFF;
    }
    __syncthreads();
    for (int i = tid; i < cntB; i += 512) csr_row[j0g + i] = sCsr[i];

    // ---- gather: degree-sorted node assignment ----
    int node = perm[nodeBase + (wid << 4) + g];   // may be N (invalid)
    bool valid = (node < N);
    int nc = valid ? node : N;                    // N = zeroed sink row
    int deg = valid ? cnt[node] : 0;
    int p = valid ? (col_ptr[node] - j0g) : 0;

    unsigned soff = (unsigned)(s << 4);
    const char* Hb = (const char*)H8in;
    uint4 us = *(const uint4*)(Hb + ((((unsigned)nc) << 6) | soff));

    int mdeg = deg;
    mdeg = max(mdeg, __shfl_xor(mdeg, 4));
    mdeg = max(mdeg, __shfl_xor(mdeg, 8));
    mdeg = max(mdeg, __shfl_xor(mdeg, 16));
    mdeg = max(mdeg, __shfl_xor(mdeg, 32));

    f32x2 a0 = {0.f,0.f}, a1 = {0.f,0.f}, a2 = {0.f,0.f}, a3 = {0.f,0.f};
    f32x2 a4 = {0.f,0.f}, a5 = {0.f,0.f}, a6 = {0.f,0.f}, a7 = {0.f,0.f};
#define ACC4(u) { a0 += cvtpk<false>((u).x); a1 += cvtpk<true>((u).x); \
                  a2 += cvtpk<false>((u).y); a3 += cvtpk<true>((u).y); \
                  a4 += cvtpk<false>((u).z); a5 += cvtpk<true>((u).z); \
                  a6 += cvtpk<false>((u).w); a7 += cvtpk<true>((u).w); }
    for (int i = 0; i < mdeg; i += 4){
        int r0 = (i     < deg) ? sCsr[p + i    ] : N;
        int r1 = (i + 1 < deg) ? sCsr[p + i + 1] : N;
        int r2 = (i + 2 < deg) ? sCsr[p + i + 2] : N;
        int r3 = (i + 3 < deg) ? sCsr[p + i + 3] : N;
        uint4 u0 = *(const uint4*)(Hb + ((((unsigned)r0) << 6) | soff));
        uint4 u1 = *(const uint4*)(Hb + ((((unsigned)r1) << 6) | soff));
        uint4 u2 = *(const uint4*)(Hb + ((((unsigned)r2) << 6) | soff));
        uint4 u3 = *(const uint4*)(Hb + ((((unsigned)r3) << 6) | soff));
        ACC4(u0) ACC4(u1) ACC4(u2) ACC4(u3)
    }
#undef ACC4
    a0 += cvtpk<false>(us.x); a1 += cvtpk<true>(us.x);
    a2 += cvtpk<false>(us.y); a3 += cvtpk<true>(us.y);
    a4 += cvtpk<false>(us.z); a5 += cvtpk<true>(us.z);
    a6 += cvtpk<false>(us.w); a7 += cvtpk<true>(us.w);

    float dv = rsqrtf((float)deg + 1.0f);
    float acc16[16] = { a0.x, a0.y, a1.x, a1.y, a2.x, a2.y, a3.x, a3.y,
                        a4.x, a4.y, a5.x, a5.y, a6.x, a6.y, a7.x, a7.y };
    float v[16], y[16];
    float4 bq[4], wq[4], cq[4];
    #pragma unroll
    for (int q = 0; q < 4; ++q){
        bq[q] = ((const float4*)bias)[(s << 2) + q];
        wq[q] = ((const float4*)lnw)[(s << 2) + q];
        cq[q] = ((const float4*)lnb)[(s << 2) + q];
    }
    #pragma unroll
    for (int j = 0; j < 16; ++j)
        v[j] = fmaf(dv, acc16[j], ((const float*)&bq[j >> 2])[j & 3]);
    float sum = 0.f;
    #pragma unroll
    for (int j = 0; j < 16; ++j) sum += v[j];
    sum += __shfl_xor(sum, 1); sum += __shfl_xor(sum, 2);
    float mu = sum * (1.0f / 64.0f);
    float var = 0.f;
    #pragma unroll
    for (int j = 0; j < 16; ++j){ float d = v[j] - mu; var = fmaf(d, d, var); }
    var += __shfl_xor(var, 1); var += __shfl_xor(var, 2);
    float rstd = rsqrtf(var * (1.0f / 64.0f) + 1e-5f);
    #pragma unroll
    for (int j = 0; j < 16; ++j){
        float d = (v[j] - mu) * rstd;
        y[j] = fmaxf(fmaf(d, ((const float*)&wq[j >> 2])[j & 3],
                             ((const float*)&cq[j >> 2])[j & 3]), 0.0f);
    }

    if (s == 0){ sdv[(wid << 4) + g] = dv; sperm[(wid << 4) + g] = nc; }
    char* yb = (char*)ybuf;
    int base = (wid << 11) + (g << 7);
    int sw = (g & 7) << 4;
    short8 ya, yz;
    #pragma unroll
    for (int j = 0; j < 8; ++j){ ya[j] = (short)f2bfbits(y[j]); yz[j] = (short)f2bfbits(y[8 + j]); }
    *(short8*)(yb + base + (((s << 5)     ) ^ sw)) = ya;
    *(short8*)(yb + base + (((s << 5) + 16) ^ sw)) = yz;

    int lr = l & 15, lg = l >> 4;
    short8 bfr[2][4];
    #pragma unroll
    for (int ks = 0; ks < 2; ++ks)
        #pragma unroll
        for (int t = 0; t < 4; ++t){
            int c = t * 16 + lr;
            int byte = c * 128 + ((((ks << 2) + lg) << 4) ^ ((c & 7) << 4));
            bfr[ks][t] = *(const short8*)((const char*)Wt + byte);
        }
    short8 af[2];
    #pragma unroll
    for (int ks = 0; ks < 2; ++ks){
        int byte = (wid << 11) + lr * 128 + ((((ks << 2) + lg) << 4) ^ ((lr & 7) << 4));
        af[ks] = *(const short8*)(yb + byte);
    }
    f32x4 acc[4] = {(f32x4)0.f, (f32x4)0.f, (f32x4)0.f, (f32x4)0.f};
    #pragma unroll
    for (int ks = 0; ks < 2; ++ks)
        #pragma unroll
        for (int t = 0; t < 4; ++t)
            acc[t] = __builtin_amdgcn_mfma_f32_16x16x32_bf16(af[ks], bfr[ks][t], acc[t], 0, 0, 0);
    #pragma unroll
    for (int r = 0; r < 4; ++r){
        int idx = (wid << 4) + (lg << 2) + r;
        int nn = sperm[idx];
        if (nn < N){
            float dv2 = sdv[idx];
            #pragma unroll
            for (int t = 0; t < 4; ++t)
                H8out[((size_t)(unsigned)nn << 6) + t * 16 + lr] = f2fp8(acc[t][r] * dv2);
        }
    }
}

// ---------------- layers 2/3: agg (perm'd) + LN + ReLU + (matmul(W3) | pool) ----------------

template<bool POOL>
__global__ __launch_bounds__(256) void agg_kernel(const unsigned char* __restrict__ H8in,
                                                  const int* __restrict__ cnt,
                                                  const int* __restrict__ col_ptr,
                                                  const int* __restrict__ csr_row,
                                                  const int* __restrict__ perm,
                                                  const float* __restrict__ bias,
                                                  const float* __restrict__ lnw,
                                                  const float* __restrict__ lnb,
                                                  const float* __restrict__ Wn,
                                                  unsigned char* __restrict__ H8out,
                                                  float* __restrict__ pooledRep, int N){
    __shared__ int sIdx[CAP];
    __shared__ __align__(16) short ybuf[POOL ? 8 : 4096];
    __shared__ __align__(16) short Wt[POOL ? 8 : 4096];
    __shared__ float sp[POOL ? 256 : 4];
    __shared__ float sdv[64];
    __shared__ int sperm[64];
    int tid = threadIdx.x;
    int wid = tid >> 6, l = tid & 63;
    int g = l >> 2, s = l & 3;
    int nodeBase = blockIdx.x * 64;

    int lastN = nodeBase + 63; if (lastN > N - 1) lastN = N - 1;
    int jlo = col_ptr[nodeBase];
    int jhi = col_ptr[lastN] + cnt[lastN];
    int cntR = jhi - jlo;

    int node = perm[nodeBase + (wid << 4) + g];   // may be N
    bool valid = (node < N);
    int nc = valid ? node : N;                    // sink row (zeroed)
    int deg = valid ? cnt[node] : 0;
    int p = valid ? (col_ptr[node] - jlo) : 0;

    for (int i = tid; i < cntR; i += 256) sIdx[i] = csr_row[jlo + i];
    if (!POOL){
        for (int i = tid; i < 4096; i += 256){
            int k = i >> 6, c = i & 63;
            unsigned short bb = f2bfbits(Wn[i]);
            int byte = c * 128 + ((2 * k) ^ ((c & 7) << 4));
            *(short*)((char*)Wt + byte) = (short)bb;
        }
    }
    __syncthreads();

    unsigned soff = (unsigned)(s << 4);
    const char* Hb = (const char*)H8in;
    uint4 us = *(const uint4*)(Hb + ((((unsigned)nc) << 6) | soff));

    int mdeg = deg;
    mdeg = max(mdeg, __shfl_xor(mdeg, 4));
    mdeg = max(mdeg, __shfl_xor(mdeg, 8));
    mdeg = max(mdeg, __shfl_xor(mdeg, 16));
    mdeg = max(mdeg, __shfl_xor(mdeg, 32));

    f32x2 a0 = {0.f,0.f}, a1 = {0.f,0.f}, a2 = {0.f,0.f}, a3 = {0.f,0.f};
    f32x2 a4 = {0.f,0.f}, a5 = {0.f,0.f}, a6 = {0.f,0.f}, a7 = {0.f,0.f};
#define ACC4(u) { a0 += cvtpk<false>((u).x); a1 += cvtpk<true>((u).x); \
                  a2 += cvtpk<false>((u).y); a3 += cvtpk<true>((u).y); \
                  a4 += cvtpk<false>((u).z); a5 += cvtpk<true>((u).z); \
                  a6 += cvtpk<false>((u).w); a7 += cvtpk<true>((u).w); }
    for (int i = 0; i < mdeg; i += 4){
        int r0 = (i     < deg) ? sIdx[p + i    ] : N;
        int r1 = (i + 1 < deg) ? sIdx[p + i + 1] : N;
        int r2 = (i + 2 < deg) ? sIdx[p + i + 2] : N;
        int r3 = (i + 3 < deg) ? sIdx[p + i + 3] : N;
        uint4 u0 = *(const uint4*)(Hb + ((((unsigned)r0) << 6) | soff));
        uint4 u1 = *(const uint4*)(Hb + ((((unsigned)r1) << 6) | soff));
        uint4 u2 = *(const uint4*)(Hb + ((((unsigned)r2) << 6) | soff));
        uint4 u3 = *(const uint4*)(Hb + ((((unsigned)r3) << 6) | soff));
        ACC4(u0) ACC4(u1) ACC4(u2) ACC4(u3)
    }
#undef ACC4
    a0 += cvtpk<false>(us.x); a1 += cvtpk<true>(us.x);
    a2 += cvtpk<false>(us.y); a3 += cvtpk<true>(us.y);
    a4 += cvtpk<false>(us.z); a5 += cvtpk<true>(us.z);
    a6 += cvtpk<false>(us.w); a7 += cvtpk<true>(us.w);

    float dv = rsqrtf((float)deg + 1.0f);
    float acc16[16] = { a0.x, a0.y, a1.x, a1.y, a2.x, a2.y, a3.x, a3.y,
                        a4.x, a4.y, a5.x, a5.y, a6.x, a6.y, a7.x, a7.y };
    float v[16], y[16];
    float4 bq[4], wq[4], cq[4];
    #pragma unroll
    for (int q = 0; q < 4; ++q){
        bq[q] = ((const float4*)bias)[(s << 2) + q];
        wq[q] = ((const float4*)lnw)[(s << 2) + q];
        cq[q] = ((const float4*)lnb)[(s << 2) + q];
    }
    #pragma unroll
    for (int j = 0; j < 16; ++j)
        v[j] = fmaf(dv, acc16[j], ((const float*)&bq[j >> 2])[j & 3]);
    float sum = 0.f;
    #pragma unroll
    for (int j = 0; j < 16; ++j) sum += v[j];
    sum += __shfl_xor(sum, 1); sum += __shfl_xor(sum, 2);
    float mu = sum * (1.0f / 64.0f);
    float var = 0.f;
    #pragma unroll
    for (int j = 0; j < 16; ++j){ float d = v[j] - mu; var = fmaf(d, d, var); }
    var += __shfl_xor(var, 1); var += __shfl_xor(var, 2);
    float rstd = rsqrtf(var * (1.0f / 64.0f) + 1e-5f);
    #pragma unroll
    for (int j = 0; j < 16; ++j){
        float d = (v[j] - mu) * rstd;
        y[j] = fmaxf(fmaf(d, ((const float*)&wq[j >> 2])[j & 3],
                             ((const float*)&cq[j >> 2])[j & 3]), 0.0f);
    }

    if (POOL){
        #pragma unroll
        for (int j = 0; j < 16; ++j){
            float z = valid ? y[j] : 0.f;
            z += __shfl_xor(z, 4); z += __shfl_xor(z, 8);
            z += __shfl_xor(z, 16); z += __shfl_xor(z, 32);
            y[j] = z;
        }
        if (l < 4){
            #pragma unroll
            for (int q = 0; q < 4; ++q)
                ((float4*)sp)[wid * 16 + (s << 2) + q] =
                    make_float4(y[4*q], y[4*q+1], y[4*q+2], y[4*q+3]);
        }
        __syncthreads();
        if (tid < 64){
            float t = sp[tid] + sp[64 + tid] + sp[128 + tid] + sp[192 + tid];
            atomicAdd(&pooledRep[(blockIdx.x & 63) * 64 + tid], t);
        }
    } else {
        if (s == 0){ sdv[(wid << 4) + g] = dv; sperm[(wid << 4) + g] = nc; }
        char* yb = (char*)ybuf;
        int base = (wid << 11) + (g << 7);
        int sw = (g & 7) << 4;
        short8 ya, yz;
        #pragma unroll
        for (int j = 0; j < 8; ++j){ ya[j] = (short)f2bfbits(y[j]); yz[j] = (short)f2bfbits(y[8 + j]); }
        *(short8*)(yb + base + (((s << 5)     ) ^ sw)) = ya;
        *(short8*)(yb + base + (((s << 5) + 16) ^ sw)) = yz;

        int lr = l & 15, lg = l >> 4;
        short8 bfr[2][4];
        #pragma unroll
        for (int ks = 0; ks < 2; ++ks)
            #pragma unroll
            for (int t = 0; t < 4; ++t){
                int c = t * 16 + lr;
                int byte = c * 128 + ((((ks << 2) + lg) << 4) ^ ((c & 7) << 4));
                bfr[ks][t] = *(const short8*)((const char*)Wt + byte);
            }
        short8 af[2];
        #pragma unroll
        for (int ks = 0; ks < 2; ++ks){
            int byte = (wid << 11) + lr * 128 + ((((ks << 2) + lg) << 4) ^ ((lr & 7) << 4));
            af[ks] = *(const short8*)(yb + byte);
        }
        f32x4 acc[4] = {(f32x4)0.f, (f32x4)0.f, (f32x4)0.f, (f32x4)0.f};
        #pragma unroll
        for (int ks = 0; ks < 2; ++ks)
            #pragma unroll
            for (int t = 0; t < 4; ++t)
                acc[t] = __builtin_amdgcn_mfma_f32_16x16x32_bf16(af[ks], bfr[ks][t], acc[t], 0, 0, 0);
        #pragma unroll
        for (int r = 0; r < 4; ++r){
            int idx = (wid << 4) + (lg << 2) + r;
            int nn = sperm[idx];
            if (nn < N){
                float dv2 = sdv[idx];
                #pragma unroll
                for (int t = 0; t < 4; ++t)
                    H8out[((size_t)(unsigned)nn << 6) + t * 16 + lr] = f2fp8(acc[t][r] * dv2);
            }
        }
    }
}

// ---------------- head: reduce 64 replicas + linear ----------------

__global__ __launch_bounds__(64) void final_kernel(const float* __restrict__ pooledRep,
                                                   const float* __restrict__ Wl,
                                                   const float* __restrict__ bl,
                                                   float* __restrict__ outp, float invN){
    __shared__ float pooled[64];
    int t = threadIdx.x;
    float s = 0.f;
    #pragma unroll 8
    for (int r = 0; r < 64; ++r) s += pooledRep[r * 64 + t];
    pooled[t] = s;
    __syncthreads();
    if (t < 25){
        float acc = bl[t];
        #pragma unroll 8
        for (int f = 0; f < HID; ++f)
            acc = fmaf(pooled[f] * invN, Wl[f * 25 + t], acc);
        outp[t] = acc;
    }
}

// ---------------- launch ----------------

static inline size_t alignup(size_t x){ return (x + 255) & ~(size_t)255; }

extern "C" void kernel_launch(void* const* d_in, const int* in_sizes, int n_in,
                              void* d_out, int out_size, void* d_ws, size_t ws_size,
                              hipStream_t stream) {
    const float* x   = (const float*)d_in[0];
    const int*   ei  = (const int*)d_in[1];
    const float* W1  = (const float*)d_in[2];
    const float* b1  = (const float*)d_in[3];
    const float* W2  = (const float*)d_in[4];
    const float* b2  = (const float*)d_in[5];
    const float* W3  = (const float*)d_in[6];
    const float* b3  = (const float*)d_in[7];
    const float* ln1w = (const float*)d_in[8];
    const float* ln1b = (const float*)d_in[9];
    const float* ln2w = (const float*)d_in[10];
    const float* ln2b = (const float*)d_in[11];
    const float* ln3w = (const float*)d_in[12];
    const float* ln3b = (const float*)d_in[13];
    const float* Wl  = (const float*)d_in[14];
    const float* bl  = (const float*)d_in[15];

    const int N = in_sizes[0] / 128;
    const int E = in_sizes[1] / 2;
    const int NB = (N + 127) >> BSH;
    const int* row = ei;
    const int* col = ei + E;

    char* p = (char*)d_ws;
    int*   gCur      = (int*)p;   p += alignup((size_t)NB * 4);
    float* pooledRep = (float*)p; p += alignup(64 * 64 * 4);
    size_t zeroBytes = (size_t)((char*)p - (char*)gCur);
    int*   binned    = (int*)p;   p += alignup((size_t)NB * CAP * 4);
    int*   csr_row   = (int*)p;   p += alignup((size_t)NB * CAP * 4);
    int*   col_ptr   = (int*)p;   p += alignup((size_t)N * 4);
    int*   cnt       = (int*)p;   p += alignup((size_t)N * 4);
    int*   perm      = (int*)p;   p += alignup((size_t)NB * 128 * 4);
    unsigned char* H8a = (unsigned char*)p; p += alignup(((size_t)N + 1) * HID);
    unsigned char* H8b = (unsigned char*)p; p += alignup(((size_t)N + 1) * HID);

    hipMemsetAsync(gCur, 0, zeroBytes, stream);

    int gB = (E + EPB - 1) / EPB;
    int gM = (N + 127) / 128;
    int gA = (N + 63) / 64;

    bin_kernel<<<gB, 1024, 0, stream>>>(row, col, E, NB, gCur, binned, H8a, H8b, N);
    degree_kernel<<<NB, 256, 0, stream>>>(gCur, binned, col_ptr, cnt, perm, N);

    // layer 1 matmul (dinv = rsqrt(cnt+1) in epilogue)
    matmul_kernel<128, float><<<gM, 256, 0, stream>>>(x, W1, cnt, H8a, N);
    // layer 1: rank-scatter + agg + LN + ReLU + fused W2 matmul
    agg_sort_kernel<<<NB, 512, 0, stream>>>(H8a, cnt, gCur, binned, col_ptr, perm, csr_row,
                                            b1, ln1w, ln1b, W2, H8b, N);
    // layer 2: agg + LN + ReLU + fused W3 matmul
    agg_kernel<false><<<gA, 256, 0, stream>>>(H8b, cnt, col_ptr, csr_row, perm,
                                              b2, ln2w, ln2b, W3, H8a, pooledRep, N);
    // layer 3: agg + LN + ReLU + mean-pool accumulate
    agg_kernel<true><<<gA, 256, 0, stream>>>(H8a, cnt, col_ptr, csr_row, perm,
                                             b3, ln3w, ln3b, nullptr, nullptr, pooledRep, N);

    final_kernel<<<1, 64, 0, stream>>>(pooledRep, Wl, bl, (float*)d_out, 1.0f / (float)N);
}

// Round 12
// 238.932 us; speedup vs baseline: 1.0385x; 1.0385x over previous
//
#include <hip/hip_runtime.h>
#include <hip/hip_bf16.h>

typedef __hip_bfloat16 bf16;
typedef __attribute__((ext_vector_type(8))) short short8;
typedef __attribute__((ext_vector_type(4))) float f32x4;
typedef __attribute__((ext_vector_type(2))) float f32x2;

#define HID 64
#define CAP 4096            // slots per 128-node bucket (mean fill ~2048; P(>4096)~0)
#define BSH 7               // bucket = node >> 7
#define EPB 2048            // edges per bin block (782 blocks; 2 blocks/CU resident)

__device__ __forceinline__ unsigned short f2bfbits(float x){
    union { float f; unsigned u; } c; c.f = x;
    unsigned r = c.u + 0x7fffu + ((c.u >> 16) & 1u);
    return (unsigned short)(r >> 16);
}
__device__ __forceinline__ unsigned char f2fp8(float x){
    unsigned v = __builtin_amdgcn_cvt_pk_fp8_f32(x, x, 0u, false);
    return (unsigned char)(v & 0xffu);
}
template<bool HI>
__device__ __forceinline__ f32x2 cvtpk(unsigned u){
    return __builtin_amdgcn_cvt_pk_f32_fp8(u, HI);
}

// ---------------- pass 1: bin edges by destination bucket (R10-proven) ----------------

__global__ __launch_bounds__(1024) void bin_kernel(const int* __restrict__ row,
                                                   const int* __restrict__ col,
                                                   int E, int NB,
                                                   int* __restrict__ gCur,
                                                   int* __restrict__ binned,
                                                   unsigned char* __restrict__ H8a,
                                                   unsigned char* __restrict__ H8b,
                                                   int N){
    __shared__ int lCnt[1024];
    __shared__ int lOff[1024];
    __shared__ int lGB[1024];
    __shared__ int sPay[EPB];
    __shared__ unsigned short sB[EPB];
    __shared__ int wSum[16];
    int tid = threadIdx.x;
    int lane = tid & 63, wv = tid >> 6;
    if (blockIdx.x == 0 && tid < 32){
        unsigned* za = (unsigned*)(H8a + ((size_t)N << 6));
        unsigned* zb = (unsigned*)(H8b + ((size_t)N << 6));
        if (tid < 16) za[tid] = 0u; else zb[tid - 16] = 0u;
    }
    int e0 = blockIdx.x * EPB;
    int eN = E - e0; if (eN > EPB) eN = EPB;

    lCnt[tid] = 0;
    int cols[2], rows[2];
    #pragma unroll
    for (int k = 0; k < 2; ++k){
        int i = tid + k * 1024;
        bool ok = (i < eN);
        cols[k] = ok ? col[e0 + i] : -1;
        rows[k] = ok ? row[e0 + i] : 0;
    }
    __syncthreads();
    #pragma unroll
    for (int k = 0; k < 2; ++k)
        if (cols[k] >= 0) atomicAdd(&lCnt[cols[k] >> BSH], 1);
    __syncthreads();

    int c = lCnt[tid];
    int inc = c;
    #pragma unroll
    for (int m = 1; m < 64; m <<= 1){
        int t = __shfl_up(inc, m);
        if (lane >= m) inc += t;
    }
    if (lane == 63) wSum[wv] = inc;
    __syncthreads();
    if (wv == 0 && lane < 16){
        int orig = wSum[lane];
        int ws = orig;
        #pragma unroll
        for (int m = 1; m < 16; m <<= 1){
            int t = __shfl_up(ws, m);
            if (lane >= m) ws += t;
        }
        wSum[lane] = ws - orig;
    }
    __syncthreads();
    int excl = inc - c + wSum[wv];
    lOff[tid] = excl;
    if (c){
        int gb = atomicAdd(&gCur[tid], c);
        lGB[tid] = tid * CAP + gb - excl;
    }
    lCnt[tid] = 0;
    __syncthreads();

    #pragma unroll
    for (int k = 0; k < 2; ++k){
        if (cols[k] >= 0){
            int bk = cols[k] >> BSH;
            int rk = atomicAdd(&lCnt[bk], 1);
            int pos = lOff[bk] + rk;
            sPay[pos] = ((cols[k] & 127) << 17) | rows[k];
            sB[pos] = (unsigned short)bk;
        }
    }
    __syncthreads();

    #pragma unroll
    for (int k = 0; k < 2; ++k){
        int i = tid + k * 1024;
        if (i < eN){
            int bk = sB[i];
            int tgt = lGB[bk] + i;
            if (tgt - (bk << 12) < CAP)
                binned[tgt] = sPay[i];
        }
    }
}

// ---------------- fused layer-1 matmul + degree/col_ptr build ----------------
// Block b = bucket b = nodes [128b, 128b+128). Prologue: histogram the bucket's
// binned entries (L2-hot, ~8KB) -> cnt/col_ptr written for downstream kernels;
// degrees kept in LDS for the dinv epilogue (no global cnt round-trip).
// Replaces the separate degree_kernel (same grid shape; one fewer dispatch).

template<int K, typename T>
__global__ __launch_bounds__(256) void matmul_kernel(const T* __restrict__ act,
                                                     const float* __restrict__ W,
                                                     const int* __restrict__ gCur,
                                                     const int* __restrict__ binned,
                                                     int* __restrict__ col_ptr,
                                                     int* __restrict__ cnt,
                                                     unsigned char* __restrict__ H8, int N){
    constexpr int KS = K / 32;
    constexpr int RB = 2 * K;
    __shared__ __align__(16) short As[128 * K];
    __shared__ __align__(16) short Wt[64 * K];
    __shared__ int fineCnt[128];
    __shared__ int scW[2];

    int tid = threadIdx.x;
    int b = blockIdx.x;
    int nodeBase = b * 128;
    int j0g = b * CAP;
    int cB = gCur[b];
    if (cB > CAP) cB = CAP;

    if (tid < 128) fineCnt[tid] = 0;

    for (int i = tid; i < K * 64; i += 256){
        int k = i >> 6, c = i & 63;
        unsigned short bb = f2bfbits(W[i]);
        int byte = c * RB + ((2 * k) ^ ((c & 7) << 4));
        *(short*)((char*)Wt + byte) = (short)bb;
    }
    constexpr int OPR = K / 8;
    for (int i = tid; i < 128 * OPR; i += 256){
        int node = i / OPR, oct = i % OPR;
        int n = nodeBase + node;
        short8 v = (short8)0;
        if (n < N){
            if constexpr (sizeof(T) == 4){
                const float4* xp = (const float4*)&act[(size_t)n * K + oct * 8];
                float4 a = xp[0], bb = xp[1];
                v[0] = (short)f2bfbits(a.x); v[1] = (short)f2bfbits(a.y);
                v[2] = (short)f2bfbits(a.z); v[3] = (short)f2bfbits(a.w);
                v[4] = (short)f2bfbits(bb.x); v[5] = (short)f2bfbits(bb.y);
                v[6] = (short)f2bfbits(bb.z); v[7] = (short)f2bfbits(bb.w);
            } else {
                v = *(const short8*)&act[(size_t)n * K + oct * 8];
            }
        }
        int byte = node * RB + ((oct * 16) ^ ((node & 7) << 4));
        *(short8*)((char*)As + byte) = v;
    }
    __syncthreads();

    // degree histogram over this bucket's binned entries (L2-hot from bin_kernel)
    for (int i = tid; i < cB; i += 256)
        atomicAdd(&fineCnt[binned[j0g + i] >> 17], 1);
    __syncthreads();
    int cf = 0, inc = 0;
    if (tid < 128){
        cf = fineCnt[tid];
        inc = cf;
        #pragma unroll
        for (int m = 1; m < 64; m <<= 1){
            int t = __shfl_up(inc, m);
            if ((tid & 63) >= m) inc += t;
        }
        if ((tid & 63) == 63) scW[tid >> 6] = inc;
    }
    __syncthreads();
    if (tid < 128){
        int off = (tid >= 64) ? scW[0] : 0;
        int node = nodeBase + tid;
        if (node < N){
            col_ptr[node] = j0g + off + inc - cf;
            cnt[node] = cf;
        }
    }
    __syncthreads();   // fineCnt stable (holds degrees) for epilogue reads

    int wv = tid >> 6, l = tid & 63;
    int lr = l & 15, lg = l >> 4;

    short8 bfr[KS][4];
    #pragma unroll
    for (int ks = 0; ks < KS; ++ks)
        #pragma unroll
        for (int t = 0; t < 4; ++t){
            int c = t * 16 + lr;
            int byte = c * RB + ((ks * 64 + lg * 16) ^ ((c & 7) << 4));
            bfr[ks][t] = *(const short8*)((const char*)Wt + byte);
        }

    #pragma unroll
    for (int nt = 0; nt < 2; ++nt){
        int nb = wv * 32 + nt * 16;
        int node = nb + lr;
        short8 af[KS];
        #pragma unroll
        for (int ks = 0; ks < KS; ++ks){
            int byte = node * RB + ((ks * 64 + lg * 16) ^ ((node & 7) << 4));
            af[ks] = *(const short8*)((const char*)As + byte);
        }
        f32x4 acc[4] = {(f32x4)0.f, (f32x4)0.f, (f32x4)0.f, (f32x4)0.f};
        #pragma unroll
        for (int ks = 0; ks < KS; ++ks)
            #pragma unroll
            for (int t = 0; t < 4; ++t)
                acc[t] = __builtin_amdgcn_mfma_f32_16x16x32_bf16(af[ks], bfr[ks][t], acc[t], 0, 0, 0);
        #pragma unroll
        for (int r = 0; r < 4; ++r){
            int loc = nb + lg * 4 + r;
            int n = nodeBase + loc;
            if (n < N){
                float dv = rsqrtf((float)fineCnt[loc] + 1.0f);
                #pragma unroll
                for (int t = 0; t < 4; ++t)
                    H8[((size_t)(unsigned)n << 6) + t * 16 + lr] = f2fp8(acc[t][r] * dv);
            }
        }
    }
}

// ---------------- layer-1 fused: rank-scatter + agg + LN + matmul(W2) (R10-proven) ----------------

__global__ __launch_bounds__(512) void agg_sort_kernel(const unsigned char* __restrict__ H8in,
                                                       const int* __restrict__ cnt,
                                                       const int* __restrict__ gCur,
                                                       const int* __restrict__ binned,
                                                       const int* __restrict__ col_ptr,
                                                       int* __restrict__ csr_row,
                                                       const float* __restrict__ bias,
                                                       const float* __restrict__ lnw,
                                                       const float* __restrict__ lnb,
                                                       const float* __restrict__ Wn,
                                                       unsigned char* __restrict__ H8out,
                                                       int N){
    __shared__ int sCsr[CAP];
    __shared__ __align__(16) short ybuf[8192];
    __shared__ __align__(16) short Wt[4096];
    __shared__ int fineCur[128];
    __shared__ float sdv[128];
    int b = blockIdx.x, tid = threadIdx.x;
    int wid = tid >> 6, l = tid & 63;
    int g = l >> 2, s = l & 3;
    int nodeBase = b << BSH;
    int n = nodeBase + wid * 16 + g;
    bool valid = (n < N);
    int nc = valid ? n : N;

    int j0g = b * CAP;
    int cntB = gCur[b];
    if (cntB > CAP) cntB = CAP;

    for (int i = tid; i < 4096; i += 512){
        int k = i >> 6, c = i & 63;
        unsigned short bb = f2bfbits(Wn[i]);
        int byte = c * 128 + ((2 * k) ^ ((c & 7) << 4));
        *(short*)((char*)Wt + byte) = (short)bb;
    }
    if (tid < 128){
        int node = nodeBase + tid;
        fineCur[tid] = (node < N) ? (col_ptr[node] - j0g) : 0;
    }
    __syncthreads();

    for (int i = tid; i < cntB; i += 512){
        int w = binned[j0g + i];
        int pos = atomicAdd(&fineCur[w >> 17], 1);
        sCsr[pos] = w & 0x1FFFF;
    }
    __syncthreads();
    for (int i = tid; i < cntB; i += 512) csr_row[j0g + i] = sCsr[i];

    int deg = valid ? cnt[nc] : 0;
    int p = valid ? (col_ptr[nc] - j0g) : 0;
    unsigned soff = (unsigned)(s << 4);
    const char* Hb = (const char*)H8in;
    uint4 us = *(const uint4*)(Hb + ((((unsigned)nc) << 6) | soff));

    int mdeg = deg;
    mdeg = max(mdeg, __shfl_xor(mdeg, 4));
    mdeg = max(mdeg, __shfl_xor(mdeg, 8));
    mdeg = max(mdeg, __shfl_xor(mdeg, 16));
    mdeg = max(mdeg, __shfl_xor(mdeg, 32));

    f32x2 a0 = {0.f,0.f}, a1 = {0.f,0.f}, a2 = {0.f,0.f}, a3 = {0.f,0.f};
    f32x2 a4 = {0.f,0.f}, a5 = {0.f,0.f}, a6 = {0.f,0.f}, a7 = {0.f,0.f};
#define ACC4(u) { a0 += cvtpk<false>((u).x); a1 += cvtpk<true>((u).x); \
                  a2 += cvtpk<false>((u).y); a3 += cvtpk<true>((u).y); \
                  a4 += cvtpk<false>((u).z); a5 += cvtpk<true>((u).z); \
                  a6 += cvtpk<false>((u).w); a7 += cvtpk<true>((u).w); }
    for (int i = 0; i < mdeg; i += 4){
        int r0 = (i     < deg) ? sCsr[p + i    ] : N;
        int r1 = (i + 1 < deg) ? sCsr[p + i + 1] : N;
        int r2 = (i + 2 < deg) ? sCsr[p + i + 2] : N;
        int r3 = (i + 3 < deg) ? sCsr[p + i + 3] : N;
        uint4 u0 = *(const uint4*)(Hb + ((((unsigned)r0) << 6) | soff));
        uint4 u1 = *(const uint4*)(Hb + ((((unsigned)r1) << 6) | soff));
        uint4 u2 = *(const uint4*)(Hb + ((((unsigned)r2) << 6) | soff));
        uint4 u3 = *(const uint4*)(Hb + ((((unsigned)r3) << 6) | soff));
        ACC4(u0) ACC4(u1) ACC4(u2) ACC4(u3)
    }
#undef ACC4
    a0 += cvtpk<false>(us.x); a1 += cvtpk<true>(us.x);
    a2 += cvtpk<false>(us.y); a3 += cvtpk<true>(us.y);
    a4 += cvtpk<false>(us.z); a5 += cvtpk<true>(us.z);
    a6 += cvtpk<false>(us.w); a7 += cvtpk<true>(us.w);

    float dv = rsqrtf((float)deg + 1.0f);
    float acc16[16] = { a0.x, a0.y, a1.x, a1.y, a2.x, a2.y, a3.x, a3.y,
                        a4.x, a4.y, a5.x, a5.y, a6.x, a6.y, a7.x, a7.y };
    float v[16], y[16];
    float4 bq[4], wq[4], cq[4];
    #pragma unroll
    for (int q = 0; q < 4; ++q){
        bq[q] = ((const float4*)bias)[(s << 2) + q];
        wq[q] = ((const float4*)lnw)[(s << 2) + q];
        cq[q] = ((const float4*)lnb)[(s << 2) + q];
    }
    #pragma unroll
    for (int j = 0; j < 16; ++j)
        v[j] = fmaf(dv, acc16[j], ((const float*)&bq[j >> 2])[j & 3]);
    float sum = 0.f;
    #pragma unroll
    for (int j = 0; j < 16; ++j) sum += v[j];
    sum += __shfl_xor(sum, 1); sum += __shfl_xor(sum, 2);
    float mu = sum * (1.0f / 64.0f);
    float var = 0.f;
    #pragma unroll
    for (int j = 0; j < 16; ++j){ float d = v[j] - mu; var = fmaf(d, d, var); }
    var += __shfl_xor(var, 1); var += __shfl_xor(var, 2);
    float rstd = rsqrtf(var * (1.0f / 64.0f) + 1e-5f);
    #pragma unroll
    for (int j = 0; j < 16; ++j){
        float d = (v[j] - mu) * rstd;
        y[j] = fmaxf(fmaf(d, ((const float*)&wq[j >> 2])[j & 3],
                             ((const float*)&cq[j >> 2])[j & 3]), 0.0f);
    }

    if (s == 0) sdv[(wid << 4) + g] = dv;
    char* yb = (char*)ybuf;
    int base = (wid << 11) + (g << 7);
    int sw = (g & 7) << 4;
    short8 ya, yz;
    #pragma unroll
    for (int j = 0; j < 8; ++j){ ya[j] = (short)f2bfbits(y[j]); yz[j] = (short)f2bfbits(y[8 + j]); }
    *(short8*)(yb + base + (((s << 5)     ) ^ sw)) = ya;
    *(short8*)(yb + base + (((s << 5) + 16) ^ sw)) = yz;

    int lr = l & 15, lg = l >> 4;
    short8 bfr[2][4];
    #pragma unroll
    for (int ks = 0; ks < 2; ++ks)
        #pragma unroll
        for (int t = 0; t < 4; ++t){
            int c = t * 16 + lr;
            int byte = c * 128 + ((((ks << 2) + lg) << 4) ^ ((c & 7) << 4));
            bfr[ks][t] = *(const short8*)((const char*)Wt + byte);
        }
    short8 af[2];
    #pragma unroll
    for (int ks = 0; ks < 2; ++ks){
        int byte = (wid << 11) + lr * 128 + ((((ks << 2) + lg) << 4) ^ ((lr & 7) << 4));
        af[ks] = *(const short8*)(yb + byte);
    }
    f32x4 acc[4] = {(f32x4)0.f, (f32x4)0.f, (f32x4)0.f, (f32x4)0.f};
    #pragma unroll
    for (int ks = 0; ks < 2; ++ks)
        #pragma unroll
        for (int t = 0; t < 4; ++t)
            acc[t] = __builtin_amdgcn_mfma_f32_16x16x32_bf16(af[ks], bfr[ks][t], acc[t], 0, 0, 0);
    #pragma unroll
    for (int r = 0; r < 4; ++r){
        int nn = nodeBase + (wid << 4) + (lg << 2) + r;
        if (nn < N){
            float dv2 = sdv[(wid << 4) + (lg << 2) + r];
            #pragma unroll
            for (int t = 0; t < 4; ++t)
                H8out[((size_t)(unsigned)nn << 6) + t * 16 + lr] = f2fp8(acc[t][r] * dv2);
        }
    }
}

// ---------------- layers 2/3: agg + LN + ReLU + (matmul(W3) | pool) (R10-proven) ----------------

template<bool POOL>
__global__ __launch_bounds__(256) void agg_kernel(const unsigned char* __restrict__ H8in,
                                                  const int* __restrict__ cnt,
                                                  const int* __restrict__ col_ptr,
                                                  const int* __restrict__ csr_row,
                                                  const float* __restrict__ bias,
                                                  const float* __restrict__ lnw,
                                                  const float* __restrict__ lnb,
                                                  const float* __restrict__ Wn,
                                                  unsigned char* __restrict__ H8out,
                                                  float* __restrict__ pooledRep, int N){
    __shared__ int sIdx[CAP];
    __shared__ __align__(16) short ybuf[POOL ? 8 : 4096];
    __shared__ __align__(16) short Wt[POOL ? 8 : 4096];
    __shared__ float sp[POOL ? 256 : 4];
    __shared__ float sdv[64];
    int tid = threadIdx.x;
    int wid = tid >> 6, l = tid & 63;
    int g = l >> 2, s = l & 3;
    int nodeBase = blockIdx.x * 64;
    int n = nodeBase + wid * 16 + g;
    bool valid = (n < N);
    int nc = valid ? n : N;

    int lastN = nodeBase + 63; if (lastN > N - 1) lastN = N - 1;
    int jlo = col_ptr[nodeBase];
    int jhi = col_ptr[lastN] + cnt[lastN];
    int cntR = jhi - jlo;

    int deg = valid ? cnt[n] : 0;
    int p = valid ? (col_ptr[n] - jlo) : 0;

    for (int i = tid; i < cntR; i += 256) sIdx[i] = csr_row[jlo + i];
    if (!POOL){
        for (int i = tid; i < 4096; i += 256){
            int k = i >> 6, c = i & 63;
            unsigned short bb = f2bfbits(Wn[i]);
            int byte = c * 128 + ((2 * k) ^ ((c & 7) << 4));
            *(short*)((char*)Wt + byte) = (short)bb;
        }
    }
    __syncthreads();

    unsigned soff = (unsigned)(s << 4);
    const char* Hb = (const char*)H8in;
    uint4 us = *(const uint4*)(Hb + ((((unsigned)nc) << 6) | soff));

    int mdeg = deg;
    mdeg = max(mdeg, __shfl_xor(mdeg, 4));
    mdeg = max(mdeg, __shfl_xor(mdeg, 8));
    mdeg = max(mdeg, __shfl_xor(mdeg, 16));
    mdeg = max(mdeg, __shfl_xor(mdeg, 32));

    f32x2 a0 = {0.f,0.f}, a1 = {0.f,0.f}, a2 = {0.f,0.f}, a3 = {0.f,0.f};
    f32x2 a4 = {0.f,0.f}, a5 = {0.f,0.f}, a6 = {0.f,0.f}, a7 = {0.f,0.f};
#define ACC4(u) { a0 += cvtpk<false>((u).x); a1 += cvtpk<true>((u).x); \
                  a2 += cvtpk<false>((u).y); a3 += cvtpk<true>((u).y); \
                  a4 += cvtpk<false>((u).z); a5 += cvtpk<true>((u).z); \
                  a6 += cvtpk<false>((u).w); a7 += cvtpk<true>((u).w); }
    for (int i = 0; i < mdeg; i += 4){
        int r0 = (i     < deg) ? sIdx[p + i    ] : N;
        int r1 = (i + 1 < deg) ? sIdx[p + i + 1] : N;
        int r2 = (i + 2 < deg) ? sIdx[p + i + 2] : N;
        int r3 = (i + 3 < deg) ? sIdx[p + i + 3] : N;
        uint4 u0 = *(const uint4*)(Hb + ((((unsigned)r0) << 6) | soff));
        uint4 u1 = *(const uint4*)(Hb + ((((unsigned)r1) << 6) | soff));
        uint4 u2 = *(const uint4*)(Hb + ((((unsigned)r2) << 6) | soff));
        uint4 u3 = *(const uint4*)(Hb + ((((unsigned)r3) << 6) | soff));
        ACC4(u0) ACC4(u1) ACC4(u2) ACC4(u3)
    }
#undef ACC4
    a0 += cvtpk<false>(us.x); a1 += cvtpk<true>(us.x);
    a2 += cvtpk<false>(us.y); a3 += cvtpk<true>(us.y);
    a4 += cvtpk<false>(us.z); a5 += cvtpk<true>(us.z);
    a6 += cvtpk<false>(us.w); a7 += cvtpk<true>(us.w);

    float dv = rsqrtf((float)deg + 1.0f);
    float acc16[16] = { a0.x, a0.y, a1.x, a1.y, a2.x, a2.y, a3.x, a3.y,
                        a4.x, a4.y, a5.x, a5.y, a6.x, a6.y, a7.x, a7.y };
    float v[16], y[16];
    float4 bq[4], wq[4], cq[4];
    #pragma unroll
    for (int q = 0; q < 4; ++q){
        bq[q] = ((const float4*)bias)[(s << 2) + q];
        wq[q] = ((const float4*)lnw)[(s << 2) + q];
        cq[q] = ((const float4*)lnb)[(s << 2) + q];
    }
    #pragma unroll
    for (int j = 0; j < 16; ++j)
        v[j] = fmaf(dv, acc16[j], ((const float*)&bq[j >> 2])[j & 3]);
    float sum = 0.f;
    #pragma unroll
    for (int j = 0; j < 16; ++j) sum += v[j];
    sum += __shfl_xor(sum, 1); sum += __shfl_xor(sum, 2);
    float mu = sum * (1.0f / 64.0f);
    float var = 0.f;
    #pragma unroll
    for (int j = 0; j < 16; ++j){ float d = v[j] - mu; var = fmaf(d, d, var); }
    var += __shfl_xor(var, 1); var += __shfl_xor(var, 2);
    float rstd = rsqrtf(var * (1.0f / 64.0f) + 1e-5f);
    #pragma unroll
    for (int j = 0; j < 16; ++j){
        float d = (v[j] - mu) * rstd;
        y[j] = fmaxf(fmaf(d, ((const float*)&wq[j >> 2])[j & 3],
                             ((const float*)&cq[j >> 2])[j & 3]), 0.0f);
    }

    if (POOL){
        #pragma unroll
        for (int j = 0; j < 16; ++j){
            float z = valid ? y[j] : 0.f;
            z += __shfl_xor(z, 4); z += __shfl_xor(z, 8);
            z += __shfl_xor(z, 16); z += __shfl_xor(z, 32);
            y[j] = z;
        }
        if (l < 4){
            #pragma unroll
            for (int q = 0; q < 4; ++q)
                ((float4*)sp)[wid * 16 + (s << 2) + q] =
                    make_float4(y[4*q], y[4*q+1], y[4*q+2], y[4*q+3]);
        }
        __syncthreads();
        if (tid < 64){
            float t = sp[tid] + sp[64 + tid] + sp[128 + tid] + sp[192 + tid];
            atomicAdd(&pooledRep[(blockIdx.x & 63) * 64 + tid], t);
        }
    } else {
        if (s == 0) sdv[(wid << 4) + g] = dv;
        char* yb = (char*)ybuf;
        int base = (wid << 11) + (g << 7);
        int sw = (g & 7) << 4;
        short8 ya, yz;
        #pragma unroll
        for (int j = 0; j < 8; ++j){ ya[j] = (short)f2bfbits(y[j]); yz[j] = (short)f2bfbits(y[8 + j]); }
        *(short8*)(yb + base + (((s << 5)     ) ^ sw)) = ya;
        *(short8*)(yb + base + (((s << 5) + 16) ^ sw)) = yz;

        int lr = l & 15, lg = l >> 4;
        short8 bfr[2][4];
        #pragma unroll
        for (int ks = 0; ks < 2; ++ks)
            #pragma unroll
            for (int t = 0; t < 4; ++t){
                int c = t * 16 + lr;
                int byte = c * 128 + ((((ks << 2) + lg) << 4) ^ ((c & 7) << 4));
                bfr[ks][t] = *(const short8*)((const char*)Wt + byte);
            }
        short8 af[2];
        #pragma unroll
        for (int ks = 0; ks < 2; ++ks){
            int byte = (wid << 11) + lr * 128 + ((((ks << 2) + lg) << 4) ^ ((lr & 7) << 4));
            af[ks] = *(const short8*)(yb + byte);
        }
        f32x4 acc[4] = {(f32x4)0.f, (f32x4)0.f, (f32x4)0.f, (f32x4)0.f};
        #pragma unroll
        for (int ks = 0; ks < 2; ++ks)
            #pragma unroll
            for (int t = 0; t < 4; ++t)
                acc[t] = __builtin_amdgcn_mfma_f32_16x16x32_bf16(af[ks], bfr[ks][t], acc[t], 0, 0, 0);
        #pragma unroll
        for (int r = 0; r < 4; ++r){
            int nn = nodeBase + (wid << 4) + (lg << 2) + r;
            if (nn < N){
                float dv2 = sdv[(wid << 4) + (lg << 2) + r];
                #pragma unroll
                for (int t = 0; t < 4; ++t)
                    H8out[((size_t)(unsigned)nn << 6) + t * 16 + lr] = f2fp8(acc[t][r] * dv2);
            }
        }
    }
}

// ---------------- head: reduce 64 replicas + linear ----------------

__global__ __launch_bounds__(64) void final_kernel(const float* __restrict__ pooledRep,
                                                   const float* __restrict__ Wl,
                                                   const float* __restrict__ bl,
                                                   float* __restrict__ outp, float invN){
    __shared__ float pooled[64];
    int t = threadIdx.x;
    float s = 0.f;
    #pragma unroll 8
    for (int r = 0; r < 64; ++r) s += pooledRep[r * 64 + t];
    pooled[t] = s;
    __syncthreads();
    if (t < 25){
        float acc = bl[t];
        #pragma unroll 8
        for (int f = 0; f < HID; ++f)
            acc = fmaf(pooled[f] * invN, Wl[f * 25 + t], acc);
        outp[t] = acc;
    }
}

// ---------------- launch ----------------

static inline size_t alignup(size_t x){ return (x + 255) & ~(size_t)255; }

extern "C" void kernel_launch(void* const* d_in, const int* in_sizes, int n_in,
                              void* d_out, int out_size, void* d_ws, size_t ws_size,
                              hipStream_t stream) {
    const float* x   = (const float*)d_in[0];
    const int*   ei  = (const int*)d_in[1];
    const float* W1  = (const float*)d_in[2];
    const float* b1  = (const float*)d_in[3];
    const float* W2  = (const float*)d_in[4];
    const float* b2  = (const float*)d_in[5];
    const float* W3  = (const float*)d_in[6];
    const float* b3  = (const float*)d_in[7];
    const float* ln1w = (const float*)d_in[8];
    const float* ln1b = (const float*)d_in[9];
    const float* ln2w = (const float*)d_in[10];
    const float* ln2b = (const float*)d_in[11];
    const float* ln3w = (const float*)d_in[12];
    const float* ln3b = (const float*)d_in[13];
    const float* Wl  = (const float*)d_in[14];
    const float* bl  = (const float*)d_in[15];

    const int N = in_sizes[0] / 128;
    const int E = in_sizes[1] / 2;
    const int NB = (N + 127) >> BSH;
    const int* row = ei;
    const int* col = ei + E;

    char* p = (char*)d_ws;
    int*   gCur      = (int*)p;   p += alignup((size_t)NB * 4);
    float* pooledRep = (float*)p; p += alignup(64 * 64 * 4);
    size_t zeroBytes = (size_t)((char*)p - (char*)gCur);
    int*   binned    = (int*)p;   p += alignup((size_t)NB * CAP * 4);
    int*   csr_row   = (int*)p;   p += alignup((size_t)NB * CAP * 4);
    int*   col_ptr   = (int*)p;   p += alignup((size_t)N * 4);
    int*   cnt       = (int*)p;   p += alignup((size_t)N * 4);
    unsigned char* H8a = (unsigned char*)p; p += alignup(((size_t)N + 1) * HID);
    unsigned char* H8b = (unsigned char*)p; p += alignup(((size_t)N + 1) * HID);

    hipMemsetAsync(gCur, 0, zeroBytes, stream);

    int gB = (E + EPB - 1) / EPB;
    int gM = (N + 127) / 128;
    int gA = (N + 63) / 64;

    bin_kernel<<<gB, 1024, 0, stream>>>(row, col, E, NB, gCur, binned, H8a, H8b, N);

    // layer 1 matmul + fused degree/col_ptr build (replaces degree_kernel)
    matmul_kernel<128, float><<<gM, 256, 0, stream>>>(x, W1, gCur, binned,
                                                      col_ptr, cnt, H8a, N);
    // layer 1: rank-scatter + agg + LN + ReLU + fused W2 matmul
    agg_sort_kernel<<<NB, 512, 0, stream>>>(H8a, cnt, gCur, binned, col_ptr, csr_row,
                                            b1, ln1w, ln1b, W2, H8b, N);
    // layer 2: agg + LN + ReLU + fused W3 matmul
    agg_kernel<false><<<gA, 256, 0, stream>>>(H8b, cnt, col_ptr, csr_row,
                                              b2, ln2w, ln2b, W3, H8a, pooledRep, N);
    // layer 3: agg + LN + ReLU + mean-pool accumulate
    agg_kernel<true><<<gA, 256, 0, stream>>>(H8a, cnt, col_ptr, csr_row,
                                             b3, ln3w, ln3b, nullptr, nullptr, pooledRep, N);

    final_kernel<<<1, 64, 0, stream>>>(pooledRep, Wl, bl, (float*)d_out, 1.0f / (float)N);
}